// Round 6
// baseline (111.640 us; speedup 1.0000x reference)
//
#include <hip/hip_runtime.h>
#include <hip/hip_bf16.h>
#include <math.h>

#define HD 256
#define BB 64
#define DD 2048
#define NCHK 16         // d-chunks per batch (128 rows each)
#define NT 4            // 32-row tiles per chunk

typedef __attribute__((ext_vector_type(8))) short  short8;
typedef __attribute__((ext_vector_type(4))) float  float4v;
typedef __attribute__((ext_vector_type(4))) unsigned short ushort4v;

__device__ inline unsigned short f2bf(float f) {
    unsigned u = __builtin_bit_cast(unsigned, f);
    u += 0x7FFFu + ((u >> 16) & 1u);   // RNE
    return (unsigned short)(u >> 16);
}
__device__ inline float bf2f(unsigned short u) {
    return __builtin_bit_cast(float, (unsigned)u << 16);
}

__device__ inline float fast_exp2(float x) {
    float r;
    asm("v_exp_f32 %0, %1" : "=v"(r) : "v"(x));
    return r;
}
__device__ inline float fast_expf(float x) { return fast_exp2(x * 1.4426950408889634f); }
__device__ inline float fast_tanh(float x) {
    float y = x * 2.8853900817779268f;          // 2x * log2(e)
    y = fminf(fmaxf(y, -30.f), 30.f);
    float t = fast_exp2(y);
    float r;
    asm("v_rcp_f32 %0, %1" : "=v"(r) : "v"(t + 1.f));
    return (t - 1.f) * r;
}

// LDS-only barrier: orders LDS traffic across waves WITHOUT draining vmcnt,
// so prefetch global loads stay in flight across it (T4).
__device__ inline void sync_lds() {
    asm volatile("s_waitcnt lgkmcnt(0)" ::: "memory");
    __builtin_amdgcn_s_barrier();
    asm volatile("" ::: "memory");
}

// ---------------- kernel 0 (fused prep): W1 f32->bf16  AND  g23 ----------------
__global__ __launch_bounds__(256) void k_prep(const float* __restrict__ W1,
                                              unsigned short* __restrict__ w1b,
                                              const float* __restrict__ ctx,
                                              const float* __restrict__ hid,
                                              const float* __restrict__ W2,
                                              const float* __restrict__ b2,
                                              const float* __restrict__ W3,
                                              float* __restrict__ g23) {
    if (blockIdx.x < 64) {
        int i = blockIdx.x * 256 + threadIdx.x;
        float4v v = ((const float4v*)W1)[i];
        ushort4v o;
        o[0] = f2bf(v[0]); o[1] = f2bf(v[1]); o[2] = f2bf(v[2]); o[3] = f2bf(v[3]);
        ((ushort4v*)w1b)[i] = o;
    } else {
        int b = blockIdx.x - 64, t = threadIdx.x;
        __shared__ float c[HD], hh[HD];
        c[t]  = ctx[b * HD + t];
        hh[t] = hid[b * HD + t];
        __syncthreads();
        const float4v* w2 = (const float4v*)(W2 + (size_t)t * HD);
        const float4v* w3 = (const float4v*)(W3 + (size_t)t * HD);
        float acc = b2[t];
        #pragma unroll 8
        for (int k = 0; k < 64; ++k) {
            float4v a = w2[k], d = w3[k];
            int k4 = k * 4;
            acc += c[k4] * a[0] + c[k4 + 1] * a[1] + c[k4 + 2] * a[2] + c[k4 + 3] * a[3];
            acc += hh[k4] * d[0] + hh[k4 + 1] * d[1] + hh[k4 + 2] * d[2] + hh[k4 + 3] * d[3];
        }
        g23[b * HD + t] = acc;
    }
}

// ---------------- kernel 1: fused scores+softmax+PV, non-draining barriers -----
// grid (16, 64), 512 thr (8 waves). Wave owns 32 h (W1 slice in 64 VGPR).
__global__ __launch_bounds__(512, 4) void k_fused(const float* __restrict__ q,
                                                  const unsigned short* __restrict__ w1b,
                                                  const float* __restrict__ g23,
                                                  const float* __restrict__ W4,
                                                  float* __restrict__ pstats,
                                                  float* __restrict__ pO) {
    __shared__ __attribute__((aligned(16))) unsigned short tile[32 * HD]; // 16 KB
    __shared__ float sp[8][32];
    __shared__ float sp2[34];
    __shared__ float g23s[HD];
    __shared__ float w4s[HD];

    const int t = threadIdx.x;
    const int chunk = blockIdx.x, b = blockIdx.y;
    const int lane = t & 63, wave = t >> 6;
    const int l15 = lane & 15, lk = lane >> 4;
    const int hb = wave * 32;

    const float* qc = q + ((size_t)(b * DD) + chunk * 128) * HD;

    // staging geometry: thread covers row sr, 16 f32 at col sc
    const int sr = t >> 4, sc = (t & 15) * 16;

    // prologue: issue tile-0 loads
    float4v st0, st1, st2, st3;
    {
        const float4v* src = (const float4v*)(qc + (size_t)sr * HD + sc);
        st0 = src[0]; st1 = src[1]; st2 = src[2]; st3 = src[3];
    }

    // W1 slice (A operand) -> 64 VGPR
    short8 bfr[8][2];
    #pragma unroll
    for (int kb = 0; kb < 8; ++kb)
        #pragma unroll
        for (int nf = 0; nf < 2; ++nf)
            bfr[kb][nf] = *(const short8*)&w1b[(size_t)(hb + nf * 16 + l15) * HD + kb * 32 + lk * 8];

    // g23 / W4 -> LDS (broadcast reads later)
    if (t < 256) g23s[t] = g23[b * HD + t];
    else         w4s[t - 256] = W4[t - 256];

    float m = -1e30f, l = 0.f;
    float4v O0 = {0.f, 0.f, 0.f, 0.f}, O1 = {0.f, 0.f, 0.f, 0.f};
    const int pg = t & 31, pr = t >> 5;   // PV: 8 cols at pg*8, rows pr & pr+16
    const int psw = (pr & 7) << 4;        // same swizzle for pr and pr+16

    sync_lds();   // g23s/w4s ready

    for (int tt = 0; tt < NT; ++tt) {
        if (tt) sync_lds();   // (A) all PV reads of prev tile done (data-dep drained lgkm)

        // convert + swizzled store (compiler waits vmcnt for st regs here)
        {
            short8 p0, p1;
            p0[0] = (short)f2bf(st0[0]); p0[1] = (short)f2bf(st0[1]);
            p0[2] = (short)f2bf(st0[2]); p0[3] = (short)f2bf(st0[3]);
            p0[4] = (short)f2bf(st1[0]); p0[5] = (short)f2bf(st1[1]);
            p0[6] = (short)f2bf(st1[2]); p0[7] = (short)f2bf(st1[3]);
            p1[0] = (short)f2bf(st2[0]); p1[1] = (short)f2bf(st2[1]);
            p1[2] = (short)f2bf(st2[2]); p1[3] = (short)f2bf(st2[3]);
            p1[4] = (short)f2bf(st3[0]); p1[5] = (short)f2bf(st3[1]);
            p1[6] = (short)f2bf(st3[2]); p1[7] = (short)f2bf(st3[3]);
            int base = sr * 512 + sc * 2;
            int sw = (sr & 7) << 4;
            *(short8*)((char*)tile + ((base) ^ sw))      = p0;
            *(short8*)((char*)tile + ((base + 16) ^ sw)) = p1;
        }

        // issue next tile's loads: fly across B/C/D/PV (raw barriers don't drain vmcnt)
        if (tt + 1 < NT) {
            const float4v* src = (const float4v*)(qc + ((size_t)((tt + 1) * 32 + sr)) * HD + sc);
            st0 = src[0]; st1 = src[1]; st2 = src[2]; st3 = src[3];
        }

        sync_lds();   // (B) tile ready

        // MFMA: C[h][d] = sum_k W1[h][k] q[d][k]
        float4v acc[2][2];
        #pragma unroll
        for (int df = 0; df < 2; ++df)
            #pragma unroll
            for (int nf = 0; nf < 2; ++nf)
                acc[df][nf] = (float4v){0.f, 0.f, 0.f, 0.f};

        #pragma unroll
        for (int kb = 0; kb < 8; ++kb) {
            short8 bq[2];
            #pragma unroll
            for (int df = 0; df < 2; ++df) {
                int d = df * 16 + l15;
                int byte = d * 512 + kb * 64 + lk * 16;
                bq[df] = *(const short8*)((const char*)tile + (byte ^ ((d & 7) << 4)));
            }
            #pragma unroll
            for (int nf = 0; nf < 2; ++nf) {
                acc[0][nf] = __builtin_amdgcn_mfma_f32_16x16x32_bf16(bfr[kb][nf], bq[0], acc[0][nf], 0, 0, 0);
                acc[1][nf] = __builtin_amdgcn_mfma_f32_16x16x32_bf16(bfr[kb][nf], bq[1], acc[1][nf], 0, 0, 0);
            }
        }

        // epilogue: tanh + W4 dot (g23/W4 via LDS broadcast), h-reduce = 2 shfl
        #pragma unroll
        for (int df = 0; df < 2; ++df) {
            float s = 0.f;
            #pragma unroll
            for (int nf = 0; nf < 2; ++nf) {
                int h0 = hb + nf * 16 + lk * 4;
                float4v g4 = *(const float4v*)&g23s[h0];
                float4v w4 = *(const float4v*)&w4s[h0];
                #pragma unroll
                for (int r = 0; r < 4; ++r)
                    s += fast_tanh(acc[df][nf][r] + g4[r]) * w4[r];
            }
            s += __shfl_xor(s, 16, 64);
            s += __shfl_xor(s, 32, 64);
            if (lk == 0) sp[wave][df * 16 + l15] = s;
        }
        sync_lds();   // (C) sp ready

        if (t < 32) {
            float s = sp[0][t] + sp[1][t] + sp[2][t] + sp[3][t]
                    + sp[4][t] + sp[5][t] + sp[6][t] + sp[7][t];
            sp2[t] = s;
            float v = s;
            v = fmaxf(v, __shfl_xor(v, 1, 32));
            v = fmaxf(v, __shfl_xor(v, 2, 32));
            v = fmaxf(v, __shfl_xor(v, 4, 32));
            v = fmaxf(v, __shfl_xor(v, 8, 32));
            v = fmaxf(v, __shfl_xor(v, 16, 32));
            float w = fast_expf(s - v);
            w += __shfl_xor(w, 1, 32);
            w += __shfl_xor(w, 2, 32);
            w += __shfl_xor(w, 4, 32);
            w += __shfl_xor(w, 8, 32);
            w += __shfl_xor(w, 16, 32);
            if (t == 0) { sp2[32] = v; sp2[33] = w; }
        }
        sync_lds();   // (D) sp2 + tile stats ready

        // online update (uniform) + PV: 2 x ds_read_b128, 16 FMA
        float tmax = sp2[32], tsum = sp2[33];
        float mn  = fmaxf(m, tmax);
        float fct = fast_expf(m - mn);
        l = l * fct + tsum * fast_expf(tmax - mn);
        float w0 = fast_expf(sp2[pr] - mn);
        float w1 = fast_expf(sp2[pr + 16] - mn);
        O0 *= fct; O1 *= fct;
        {
            int byte0 = (pr * 512 + pg * 16) ^ psw;
            int byte1 = ((pr + 16) * 512 + pg * 16) ^ psw;
            short8 v0 = *(const short8*)((const char*)tile + byte0);
            short8 v1 = *(const short8*)((const char*)tile + byte1);
            #pragma unroll
            for (int j = 0; j < 4; ++j) {
                O0[j] += w0 * bf2f((unsigned short)v0[j]) + w1 * bf2f((unsigned short)v1[j]);
                O1[j] += w0 * bf2f((unsigned short)v0[j + 4]) + w1 * bf2f((unsigned short)v1[j + 4]);
            }
        }
        m = mn;
    }

    // final: reduce O over the 16 pr-groups per column (reuse tile as f32 scratch)
    sync_lds();
    float* ofin = (float*)tile;            // 16 KB = 16 x 256 floats
    *(float4v*)&ofin[pr * 256 + pg * 8]     = O0;
    *(float4v*)&ofin[pr * 256 + pg * 8 + 4] = O1;
    sync_lds();
    if (t < 256) {
        float s = 0.f;
        #pragma unroll
        for (int rr = 0; rr < 16; ++rr) s += ofin[rr * 256 + t];
        pO[((size_t)(b * NCHK + chunk)) * HD + t] = s;
        if (t == 0) {
            pstats[(b * NCHK + chunk) * 2]     = m;
            pstats[(b * NCHK + chunk) * 2 + 1] = l;
        }
    }
}

// ---------------- kernel 2: combine 16 chunk-partials per batch ----------------
__global__ __launch_bounds__(256) void k_comb(const float* __restrict__ pstats,
                                              const float* __restrict__ pO,
                                              float* __restrict__ out) {
    int b = blockIdx.x, t = threadIdx.x;
    float M = -1e30f;
    #pragma unroll
    for (int c = 0; c < NCHK; ++c) M = fmaxf(M, pstats[(b * NCHK + c) * 2]);
    float L = 0.f, s = 0.f;
    #pragma unroll
    for (int c = 0; c < NCHK; ++c) {
        float f = fast_expf(pstats[(b * NCHK + c) * 2] - M);
        L += f * pstats[(b * NCHK + c) * 2 + 1];
        s += f * pO[((size_t)(b * NCHK + c)) * HD + t];
    }
    out[b * HD + t] = s / L;
}

extern "C" void kernel_launch(void* const* d_in, const int* in_sizes, int n_in,
                              void* d_out, int out_size, void* d_ws, size_t ws_size,
                              hipStream_t stream) {
    (void)in_sizes; (void)n_in; (void)out_size; (void)ws_size;
    const float* ctx = (const float*)d_in[0];
    const float* q   = (const float*)d_in[1];
    const float* hid = (const float*)d_in[2];
    const float* W1  = (const float*)d_in[3];
    const float* W2  = (const float*)d_in[4];
    const float* b2  = (const float*)d_in[5];
    const float* W3  = (const float*)d_in[6];
    const float* W4  = (const float*)d_in[7];
    // d_in[8] = b4: dropped (softmax shift-invariant)
    float* out = (float*)d_out;

    char* ws = (char*)d_ws;
    unsigned short* w1b = (unsigned short*)(ws);            // 131072 B
    float* g23    = (float*)(ws + 131072);                  //  65536 B
    float* pstats = (float*)(ws + 196608);                  //   8192 B
    float* pO     = (float*)(ws + 204800);                  // 1048576 B

    k_prep <<<dim3(128), dim3(256), 0, stream>>>(W1, w1b, ctx, hid, W2, b2, W3, g23);
    k_fused<<<dim3(NCHK, BB), dim3(512), 0, stream>>>(q, w1b, g23, W4, pstats, pO);
    k_comb <<<dim3(BB), dim3(256), 0, stream>>>(pstats, pO, out);
}